// Round 4
// baseline (535.878 us; speedup 1.0000x reference)
//
#include <hip/hip_runtime.h>
#include <stdint.h>

// ---- problem constants ----
#define B_ 4
#define S_ 1024
#define E_ 1024
#define H_ 16
#define D_ 64

typedef unsigned short u16;
typedef short s16x8 __attribute__((ext_vector_type(8)));
typedef unsigned short u16x8 __attribute__((ext_vector_type(8)));
typedef unsigned short u16x4 __attribute__((ext_vector_type(4)));
typedef unsigned short u16x2 __attribute__((ext_vector_type(2)));
typedef float f32x4 __attribute__((ext_vector_type(4)));

__device__ __forceinline__ u16 f2bf(float f) {
    union { float f; uint32_t i; } x; x.f = f;
    uint32_t r = (x.i + 0x7FFFu + ((x.i >> 16) & 1u)) >> 16;
    return (u16)r;
}

__device__ __forceinline__ float wave_sum(float v) {
    #pragma unroll
    for (int o = 32; o; o >>= 1) v += __shfl_xor(v, o);
    return v;
}

// async global->LDS, 16B per lane. LDS dest = wave-uniform base + lane*16.
__device__ __forceinline__ void gload16(const u16* g, u16* l) {
    __builtin_amdgcn_global_load_lds(
        (const __attribute__((address_space(1))) void*)g,
        (__attribute__((address_space(3))) void*)l, 16, 0, 0);
}

// =====================================================================
// Double-buffered GEMM core (T3-minimum): C += A (M x K bf16, lda) *
// BT^T (BT: N x K bf16, ldb). BK=32, 256 threads = 4 waves (2x2).
// STAGE(next) issued BEFORE compute(cur); one vmcnt(0)+barrier per
// K-step -> global latency hides under ds_read+MFMA.
// =====================================================================
template<int BM, int BN>
__device__ __forceinline__ void gemm_core(
    const u16* __restrict__ Ab, int lda,
    const u16* __restrict__ Bp, int ldb,
    int m0, int n0, int K,
    u16* As, u16* Bs, f32x4 (&acc)[BM / 32][BN / 32])
{
    constexpr int FM = BM / 32, FN = BN / 32;
    constexpr int ACH = BM / 64;            // 16B chunks per thread for A
    constexpr int BCH = BN / 64;            // 16B chunks per thread for B
    const int t = threadIdx.x, lane = t & 63, w = t >> 6;
    const int wr = w >> 1, wc = w & 1, al = lane & 15, aq = lane >> 4;

    auto stage = [&](int buf, int k0) {
        u16* Ad = As + buf * (BM * 32);
        u16* Bd = Bs + buf * (BN * 32);
        #pragma unroll
        for (int i = 0; i < ACH; i++) {
            const int c = i * 256 + w * 64 + lane;           // chunk id
            gload16(Ab + (size_t)(m0 + (c >> 2)) * lda + k0 + (c & 3) * 8,
                    Ad + (size_t)(i * 256 + w * 64) * 8);
        }
        #pragma unroll
        for (int i = 0; i < BCH; i++) {
            const int c = i * 256 + w * 64 + lane;
            gload16(Bp + (size_t)(n0 + (c >> 2)) * ldb + k0 + (c & 3) * 8,
                    Bd + (size_t)(i * 256 + w * 64) * 8);
        }
    };
    auto compute = [&](int buf) {
        const u16* Ar = As + buf * (BM * 32);
        const u16* Br = Bs + buf * (BN * 32);
        s16x8 af[FM], bf[FN];
        #pragma unroll
        for (int i = 0; i < FM; i++)
            af[i] = *(const s16x8*)(Ar + ((wr * FM + i) * 16 + al) * 32 + aq * 8);
        #pragma unroll
        for (int j = 0; j < FN; j++)
            bf[j] = *(const s16x8*)(Br + ((wc * FN + j) * 16 + al) * 32 + aq * 8);
        #pragma unroll
        for (int i = 0; i < FM; i++)
            #pragma unroll
            for (int j = 0; j < FN; j++)
                acc[i][j] = __builtin_amdgcn_mfma_f32_16x16x32_bf16(af[i], bf[j], acc[i][j], 0, 0, 0);
    };

    int cur = 0;
    stage(0, 0);
    for (int k0 = 32; k0 < K; k0 += 32) {
        asm volatile("s_waitcnt vmcnt(0)" ::: "memory");
        __syncthreads();
        stage(cur ^ 1, k0);      // async: flies under compute(cur)
        compute(cur);
        cur ^= 1;
    }
    asm volatile("s_waitcnt vmcnt(0)" ::: "memory");
    __syncthreads();
    compute(cur);
}

// ---- fused Q/K/V projections: one dispatch. XCD mapping keeps the 8
// blocks sharing an A-panel on one XCD's L2. ----
__global__ __launch_bounds__(256, 3)
void gemm_qkv(const u16* __restrict__ qbf, const u16* __restrict__ kbf,
              const u16* __restrict__ vbf, const u16* __restrict__ wt,
              const float* __restrict__ bq, const float* __restrict__ bk,
              const float* __restrict__ bv,
              u16* __restrict__ q_ws, u16* __restrict__ k_ws,
              u16* __restrict__ vt_ws)
{
    __shared__ __attribute__((aligned(16))) u16 As[2 * 128 * 32];
    __shared__ __attribute__((aligned(16))) u16 Bs[2 * 128 * 32];
    const int flat = blockIdx.x + (blockIdx.y << 3) + (blockIdx.z << 8);
    const int z = flat >> 8;
    const int y = flat & 31;
    const int x = (flat >> 5) & 7;
    const u16* Ab = (z == 0) ? qbf : (z == 1) ? kbf : vbf;
    const u16* Bp = wt + (size_t)z * E_ * E_;
    const float* bias = (z == 0) ? bq : (z == 1) ? bk : bv;
    u16* Cb = (z == 0) ? q_ws : (z == 1) ? k_ws : vt_ws;
    const int m0 = y * 128, n0 = x * 128;

    f32x4 acc[4][4];
    #pragma unroll
    for (int i = 0; i < 4; i++)
        #pragma unroll
        for (int j = 0; j < 4; j++)
            acc[i][j] = (f32x4){0.f, 0.f, 0.f, 0.f};

    gemm_core<128, 128>(Ab, E_, Bp, E_, m0, n0, E_, As, Bs, acc);

    const int t = threadIdx.x, lane = t & 63, w = t >> 6;
    const int wr = w >> 1, wc = w & 1, al = lane & 15, aq = lane >> 4;
    #pragma unroll
    for (int i = 0; i < 4; i++) {
        #pragma unroll
        for (int j = 0; j < 4; j++) {
            const int col = n0 + (wc * 4 + j) * 16 + al;
            const float bvv = bias[col];
            #pragma unroll
            for (int r = 0; r < 4; r++) {
                const int row = m0 + (wr * 4 + i) * 16 + aq * 4 + r;
                const float vv = acc[i][j][r] + bvv;
                const int b = row >> 10, s = row & 1023, h = col >> 6, d = col & 63;
                if (z < 2)
                    Cb[((size_t)((b * H_ + h) * S_ + s)) * D_ + d] = f2bf(vv);
                else
                    Cb[((size_t)((b * H_ + h) * D_ + d)) * S_ + s] = f2bf(vv);
            }
        }
    }
}

// ---- output projection: C = ctx(bf16) @ Wo^T + bo -> f32 (nt store) ----
__global__ __launch_bounds__(256, 3)
void gemm_o(const u16* __restrict__ ctx, const u16* __restrict__ wt3,
            const float* __restrict__ bo, float* __restrict__ out)
{
    __shared__ __attribute__((aligned(16))) u16 As[2 * 128 * 32];
    __shared__ __attribute__((aligned(16))) u16 Bs[2 * 64 * 32];
    const int flat = blockIdx.x + (blockIdx.y << 4);
    const int y = flat & 31;
    const int x = flat >> 5;           // 0..15
    const int m0 = y * 128, n0 = x * 64;

    f32x4 acc[4][2];
    #pragma unroll
    for (int i = 0; i < 4; i++)
        #pragma unroll
        for (int j = 0; j < 2; j++)
            acc[i][j] = (f32x4){0.f, 0.f, 0.f, 0.f};

    gemm_core<128, 64>(ctx, E_, wt3, E_, m0, n0, E_, As, Bs, acc);

    const int t = threadIdx.x, lane = t & 63, w = t >> 6;
    const int wr = w >> 1, wc = w & 1, al = lane & 15, aq = lane >> 4;
    #pragma unroll
    for (int i = 0; i < 4; i++) {
        #pragma unroll
        for (int j = 0; j < 2; j++) {
            const int col = n0 + (wc * 2 + j) * 16 + al;
            const float bvv = bo[col];
            #pragma unroll
            for (int r = 0; r < 4; r++) {
                const int row = m0 + (wr * 4 + i) * 16 + aq * 4 + r;
                __builtin_nontemporal_store(acc[i][j][r] + bvv,
                                            &out[(size_t)row * E_ + col]);
            }
        }
    }
}

// =====================================================================
// Fused prelude: one dispatch, blocks partitioned by range.
//   [0, 512)        : f32->bf16 convert of q/k/v
//   [512, 1536)     : 4 x ExE transpose+convert, 64x64 tiles
//   [1536, 2560)    : consciousness weights (4 rows/block)
// =====================================================================
__global__ __launch_bounds__(256)
void prelude_k(const float* __restrict__ query, const float* __restrict__ key_,
               const float* __restrict__ value,
               const float* __restrict__ Wq, const float* __restrict__ Wk,
               const float* __restrict__ Wv, const float* __restrict__ Wo,
               const float* __restrict__ Wc, const float* __restrict__ bc,
               const float* __restrict__ cl,
               u16* __restrict__ qbf, u16* __restrict__ kbf,
               u16* __restrict__ vbf, u16* __restrict__ wt,
               float* __restrict__ mws)
{
    __shared__ float tile[64][65];
    const int bid = blockIdx.x, t = threadIdx.x;

    if (bid < 512) {
        const int tid = bid * 256 + t;
        #pragma unroll
        for (int j = 0; j < 4; j++) {
            const int i = tid + j * 131072;
            {
                f32x4 a = *(const f32x4*)(query + (size_t)i * 8);
                f32x4 b = *(const f32x4*)(query + (size_t)i * 8 + 4);
                u16x8 o;
                o[0] = f2bf(a[0]); o[1] = f2bf(a[1]); o[2] = f2bf(a[2]); o[3] = f2bf(a[3]);
                o[4] = f2bf(b[0]); o[5] = f2bf(b[1]); o[6] = f2bf(b[2]); o[7] = f2bf(b[3]);
                *(u16x8*)(qbf + (size_t)i * 8) = o;
            }
            {
                f32x4 a = *(const f32x4*)(key_ + (size_t)i * 8);
                f32x4 b = *(const f32x4*)(key_ + (size_t)i * 8 + 4);
                u16x8 o;
                o[0] = f2bf(a[0]); o[1] = f2bf(a[1]); o[2] = f2bf(a[2]); o[3] = f2bf(a[3]);
                o[4] = f2bf(b[0]); o[5] = f2bf(b[1]); o[6] = f2bf(b[2]); o[7] = f2bf(b[3]);
                *(u16x8*)(kbf + (size_t)i * 8) = o;
            }
            {
                f32x4 a = *(const f32x4*)(value + (size_t)i * 8);
                f32x4 b = *(const f32x4*)(value + (size_t)i * 8 + 4);
                u16x8 o;
                o[0] = f2bf(a[0]); o[1] = f2bf(a[1]); o[2] = f2bf(a[2]); o[3] = f2bf(a[3]);
                o[4] = f2bf(b[0]); o[5] = f2bf(b[1]); o[6] = f2bf(b[2]); o[7] = f2bf(b[3]);
                *(u16x8*)(vbf + (size_t)i * 8) = o;
            }
        }
    } else if (bid < 1536) {
        const int tb = bid - 512;
        const int zz = tb >> 8, rem = tb & 255;
        const int by = (rem >> 4) * 64, bx = (rem & 15) * 64;
        const float* in = (zz == 0) ? Wq : (zz == 1) ? Wk : (zz == 2) ? Wv : Wo;
        u16* o = wt + (size_t)zz * E_ * E_;
        const int tx = t & 63, ty = t >> 6;       // 64 cols x 4 rows
        #pragma unroll
        for (int i = 0; i < 16; i++) {
            const int r = ty + i * 4;
            tile[r][tx] = in[(size_t)(by + r) * E_ + bx + tx];
        }
        __syncthreads();
        #pragma unroll
        for (int i = 0; i < 16; i++) {
            const int r = ty + i * 4;
            o[(size_t)(bx + r) * E_ + by + tx] = f2bf(tile[tx][r]);
        }
    } else {
        const int lane = t & 63, wave = t >> 6;
        const int r = (bid - 1536) * 4 + wave;    // row in [0, B*S)
        const float* qrow = query + (size_t)r * E_;
        float acc[H_];
        #pragma unroll
        for (int c = 0; c < H_; c++) acc[c] = 0.f;
        for (int e = lane; e < E_; e += 64) {
            float qv = qrow[e];
            const float* wp = Wc + e * H_;
            f32x4 w0 = *(const f32x4*)(wp);
            f32x4 w1 = *(const f32x4*)(wp + 4);
            f32x4 w2 = *(const f32x4*)(wp + 8);
            f32x4 w3 = *(const f32x4*)(wp + 12);
            #pragma unroll
            for (int c = 0; c < 4; c++) {
                acc[c]      += qv * w0[c];
                acc[4 + c]  += qv * w1[c];
                acc[8 + c]  += qv * w2[c];
                acc[12 + c] += qv * w3[c];
            }
        }
        #pragma unroll
        for (int c = 0; c < H_; c++) acc[c] = wave_sum(acc[c]);
        float mx = -3e38f;
        #pragma unroll
        for (int c = 0; c < H_; c++) { acc[c] += bc[c]; mx = fmaxf(mx, acc[c]); }
        float se = 0.f;
        #pragma unroll
        for (int c = 0; c < H_; c++) { acc[c] = __expf(acc[c] - mx); se += acc[c]; }
        if (lane < H_) {
            float mycw = 0.f;
            #pragma unroll
            for (int c = 0; c < H_; c++) if (lane == c) mycw = acc[c];
            mycw /= se;
            int b = r >> 10, s = r & 1023;
            float clv = cl[r];
            mws[((size_t)(b * H_ + lane)) * S_ + s] = 1.f + clv * mycw;
        }
    }
}

// =====================================================================
// Fused attention. 512 threads (8 waves), one (b,h) x 16-row Q tile.
// Swapped-operand MFMA (D: col=q, row=4-consecutive-k) so softmax runs
// in regs with scalar per-thread row-sums AND e2 stages to LDS with
// vectorized b128 writes; attn then written fully-coalesced (16B/lane
// nt f32x4 from LDS). PV reads f32 from LDS + f2bf (R1-proven pattern).
// LDS 66.4 KB -> 2 blocks/CU (16 waves/CU).
// =====================================================================
#define LDS_ 1028   // f32 row stride: 1028%32=4 -> 2-way (free) on PV reads
__global__ __launch_bounds__(512, 4)
void attn_fused(const u16* __restrict__ q_ws, const u16* __restrict__ k_ws,
                const u16* __restrict__ vt_ws, const float* __restrict__ mws,
                float* __restrict__ attn_out, u16* __restrict__ ctx_ws,
                float alpha)
{
    __shared__ __attribute__((aligned(16))) float Sf[16 * LDS_]; // 65792B
    float* dmp = Sf;                    // [8][64][20] f32 (reduction, after barrier)
    __shared__ float red[8 * 16];
    __shared__ float sclA[16], invzA[16];

    const int t = threadIdx.x, lane = t & 63, w = t >> 6;
    const int al = lane & 15, aq = lane >> 4;
    // bh = blockIdx.x: round-robin dispatch puts all 64 q-tiles of one
    // (b,h) on XCD bh%8 -> K/V (256KB x 8 bh) L2-resident per XCD.
    const int bh = blockIdx.x;
    const int q0 = blockIdx.y << 4;

    const u16* Qp = q_ws + ((size_t)bh * S_ + q0) * D_;
    const u16* Kp = k_ws + ((size_t)bh * S_ + w * 128) * D_;
    const u16* Vp = vt_ws + (size_t)bh * D_ * S_;

    // ---------- phase 1: scores + exp, regs. D: col=q (al), row=k ----------
    s16x8 qb0 = *(const s16x8*)(Qp + (size_t)al * D_ + aq * 8);
    s16x8 qb1 = *(const s16x8*)(Qp + (size_t)al * D_ + 32 + aq * 8);
    const int qg = q0 + al;             // this thread's q (column)
    f32x4 ee[8];
    float s1 = 0.f;
    #pragma unroll
    for (int mf = 0; mf < 8; mf++) {
        const u16* kr = Kp + (size_t)(mf * 16 + al) * D_ + aq * 8;
        s16x8 ka0 = *(const s16x8*)(kr);
        s16x8 ka1 = *(const s16x8*)(kr + 32);
        f32x4 a0 = (f32x4){0.f, 0.f, 0.f, 0.f};
        a0 = __builtin_amdgcn_mfma_f32_16x16x32_bf16(ka0, qb0, a0, 0, 0, 0);
        a0 = __builtin_amdgcn_mfma_f32_16x16x32_bf16(ka1, qb1, a0, 0, 0, 0);
        const int k0i = w * 128 + mf * 16 + aq * 4;   // first of 4 consecutive k
        #pragma unroll
        for (int r = 0; r < 4; r++) {
            float e = (k0i + r <= qg) ? __expf(a0[r] * alpha) : 0.f;
            ee[mf][r] = e;
            s1 += e;
        }
    }
    // sum over the 4 aq-groups (same q = al): xor 16, 32
    s1 += __shfl_xor(s1, 16);
    s1 += __shfl_xor(s1, 32);
    if (lane < 16) red[w * 16 + al] = s1;
    __syncthreads();
    if (t < 16) {
        float s = 0.f;
        #pragma unroll
        for (int c = 0; c < 8; c++) s += red[c * 16 + t];
        sclA[t] = mws[(size_t)bh * S_ + q0 + t] / s;   // m / sum1
    }
    __syncthreads();

    // ---------- pass 3: e2 = exp(e1*scl) (masked -> 1), Z over ALL cols ----------
    const float sl = sclA[al];
    float s2 = 0.f;
    #pragma unroll
    for (int mf = 0; mf < 8; mf++) {
        const int k0i = w * 128 + mf * 16 + aq * 4;
        #pragma unroll
        for (int r = 0; r < 4; r++) {
            float e = (k0i + r <= qg) ? __expf(ee[mf][r] * sl) : 1.f;
            ee[mf][r] = e;
            s2 += e;
        }
    }
    s2 += __shfl_xor(s2, 16);
    s2 += __shfl_xor(s2, 32);
    if (lane < 16) red[w * 16 + al] = s2;
    __syncthreads();
    if (t < 16) {
        float s = 0.f;
        #pragma unroll
        for (int c = 0; c < 8; c++) s += red[c * 16 + t];
        invzA[t] = 1.f / s;
    }
    // ---------- stage e2 -> Sf[q][k], vectorized b128 along k ----------
    #pragma unroll
    for (int mf = 0; mf < 8; mf++) {
        const int k0i = w * 128 + mf * 16 + aq * 4;
        *(f32x4*)(Sf + (size_t)al * LDS_ + k0i) = ee[mf];
    }
    __syncthreads();

    // ---------- attn write: fully-coalesced nt f32x4 from LDS ----------
    // wave w owns rows 2w, 2w+1; 1KB contiguous per wave-instr.
    float* ao = attn_out + (size_t)bh * S_ * S_ + (size_t)q0 * S_;
    #pragma unroll
    for (int rr = 0; rr < 2; rr++) {
        const int r2 = w * 2 + rr;
        const float iz = invzA[r2];
        #pragma unroll
        for (int k2 = 0; k2 < 4; k2++) {
            f32x4 v = *(const f32x4*)(Sf + (size_t)r2 * LDS_ + k2 * 256 + lane * 4);
            f32x4 o;
            #pragma unroll
            for (int j = 0; j < 4; j++) o[j] = v[j] * iz;
            __builtin_nontemporal_store(o, (f32x4*)(ao + (size_t)r2 * S_ + k2 * 256 + lane * 4));
        }
    }

    // ---------- PV partials, wave w covers k in [w*128, w*128+128) ----------
    f32x4 pa[4];
    #pragma unroll
    for (int nf = 0; nf < 4; nf++) pa[nf] = (f32x4){0.f, 0.f, 0.f, 0.f};
    #pragma unroll
    for (int ks = 0; ks < 4; ks++) {
        const int kb = w * 128 + ks * 32;
        const float* ap = Sf + (size_t)al * LDS_ + kb + aq * 8;
        f32x4 x0 = *(const f32x4*)(ap);
        f32x4 x1 = *(const f32x4*)(ap + 4);
        s16x8 af;
        af[0] = (short)f2bf(x0[0]); af[1] = (short)f2bf(x0[1]);
        af[2] = (short)f2bf(x0[2]); af[3] = (short)f2bf(x0[3]);
        af[4] = (short)f2bf(x1[0]); af[5] = (short)f2bf(x1[1]);
        af[6] = (short)f2bf(x1[2]); af[7] = (short)f2bf(x1[3]);
        #pragma unroll
        for (int nf = 0; nf < 4; nf++) {
            s16x8 bv = *(const s16x8*)(Vp + (size_t)(nf * 16 + al) * S_ + kb + aq * 8);
            pa[nf] = __builtin_amdgcn_mfma_f32_16x16x32_bf16(af, bv, pa[nf], 0, 0, 0);
        }
    }
    __syncthreads();   // all Sf reads done -> reuse LDS as reduction scratch

    // ---------- cross-wave ctx reduction, store bf16 ctx ----------
    {
        float* dp = dmp + w * (64 * 20);
        #pragma unroll
        for (int nf = 0; nf < 4; nf++)
            *(f32x4*)(dp + (size_t)(nf * 16 + al) * 20 + aq * 4) = pa[nf];
    }
    __syncthreads();
    {
        const int r5 = t >> 5, d0 = (t & 31) * 2;
        const float iz = invzA[r5];
        float o0 = 0.f, o1 = 0.f;
        #pragma unroll
        for (int ww = 0; ww < 8; ww++) {
            const float* rp5 = dmp + ww * (64 * 20) + r5;
            o0 += rp5[(size_t)d0 * 20];
            o1 += rp5[(size_t)(d0 + 1) * 20];
        }
        const int b = bh >> 4, h = bh & 15;
        u16* cp = ctx_ws + ((size_t)(b * S_ + q0 + r5)) * E_ + h * 64 + d0;
        u16x2 ob;
        ob[0] = f2bf(o0 * iz);
        ob[1] = f2bf(o1 * iz);
        *(u16x2*)cp = ob;
    }
}

extern "C" void kernel_launch(void* const* d_in, const int* in_sizes, int n_in,
                              void* d_out, int out_size, void* d_ws, size_t ws_size,
                              hipStream_t stream)
{
    const float* query = (const float*)d_in[0];
    const float* key_  = (const float*)d_in[1];
    const float* value = (const float*)d_in[2];
    const float* cl    = (const float*)d_in[3];
    // d_in[4] = attn_mask (tril, constant) -- causality handled analytically
    const float* Wq = (const float*)d_in[5];
    const float* bq = (const float*)d_in[6];
    const float* Wk = (const float*)d_in[7];
    const float* bk = (const float*)d_in[8];
    const float* Wv = (const float*)d_in[9];
    const float* bv = (const float*)d_in[10];
    const float* Wo = (const float*)d_in[11];
    const float* bo = (const float*)d_in[12];
    const float* Wc = (const float*)d_in[13];
    const float* bc = (const float*)d_in[14];
    // d_in[15] = phi_bias: per-row constant inside softmax1 -> cancels

    float* out  = (float*)d_out;
    float* attn = out + (size_t)B_ * S_ * E_;        // [B][H][S][S] f32

    u16* q_ws   = (u16*)d_ws;                        // [B][H][S][D] bf16
    u16* k_ws   = q_ws  + (size_t)B_ * S_ * E_;      // [B][H][S][D]
    u16* vt_ws  = k_ws  + (size_t)B_ * S_ * E_;      // [B][H][D][S]
    u16* ctx_ws = vt_ws + (size_t)B_ * S_ * E_;      // [B][S][E]
    u16* wt     = ctx_ws + (size_t)B_ * S_ * E_;     // 4 x [E][E] bf16 W^T
    float* mws  = (float*)(wt + (size_t)4 * E_ * E_); // [B][H][S] f32

    // bf16 copies of query/key/value live in the (later fully overwritten)
    // attn output region: 24 MB scratch inside the 268 MB attn buffer.
    u16* qbf = (u16*)attn;
    u16* kbf = qbf + (size_t)B_ * S_ * E_;
    u16* vbf = kbf + (size_t)B_ * S_ * E_;

    const float inv_scale = 0.09826892502579689f;    // 1/(8*sqrt(PHI))
    dim3 blk(256);

    // fused prelude: cvt3 (512 blocks) + W transposes (1024) + cons (1024)
    prelude_k<<<2560, blk, 0, stream>>>(query, key_, value, Wq, Wk, Wv, Wo,
                                        Wc, bc, cl, qbf, kbf, vbf, wt, mws);

    // fused Q/K/V projections: M=4096, N=1024, K=1024, 768 blocks (3/CU)
    gemm_qkv<<<dim3(8, 32, 3), blk, 0, stream>>>(
        qbf, kbf, vbf, wt, bq, bk, bv, q_ws, k_ws, vt_ws);

    // fused scores + double-softmax + attn write + PV (16-row Q tiles)
    attn_fused<<<dim3(B_ * H_, S_ / 16), dim3(512), 0, stream>>>(
        q_ws, k_ws, vt_ws, mws, attn, ctx_ws, inv_scale);

    // output projection: M=4096, N=1024, K=1024 (A bf16); 512 blocks
    gemm_o<<<dim3(16, 32, 1), blk, 0, stream>>>(
        ctx_ws, wt + (size_t)3 * E_ * E_, bo, out);
}

// Round 5
// 510.040 us; speedup vs baseline: 1.0507x; 1.0507x over previous
//
#include <hip/hip_runtime.h>
#include <stdint.h>

// ---- problem constants ----
#define B_ 4
#define S_ 1024
#define E_ 1024
#define H_ 16
#define D_ 64

typedef unsigned short u16;
typedef short s16x8 __attribute__((ext_vector_type(8)));
typedef unsigned short u16x8 __attribute__((ext_vector_type(8)));
typedef unsigned short u16x4 __attribute__((ext_vector_type(4)));
typedef unsigned short u16x2 __attribute__((ext_vector_type(2)));
typedef float f32x4 __attribute__((ext_vector_type(4)));

__device__ __forceinline__ u16 f2bf(float f) {
    union { float f; uint32_t i; } x; x.f = f;
    uint32_t r = (x.i + 0x7FFFu + ((x.i >> 16) & 1u)) >> 16;
    return (u16)r;
}

__device__ __forceinline__ float bf2f(u16 u) {
    union { uint32_t i; float f; } x; x.i = ((uint32_t)u) << 16;
    return x.f;
}

__device__ __forceinline__ float wave_sum(float v) {
    #pragma unroll
    for (int o = 32; o; o >>= 1) v += __shfl_xor(v, o);
    return v;
}

// async global->LDS, 16B per lane. LDS dest = wave-uniform base + lane*16.
__device__ __forceinline__ void gload16(const u16* g, u16* l) {
    __builtin_amdgcn_global_load_lds(
        (const __attribute__((address_space(1))) void*)g,
        (__attribute__((address_space(3))) void*)l, 16, 0, 0);
}

// =====================================================================
// Double-buffered GEMM core (T3-minimum): C += A (M x K bf16, lda) *
// BT^T (BT: N x K bf16, ldb). BK=32, 256 threads = 4 waves (2x2).
// =====================================================================
template<int BM, int BN>
__device__ __forceinline__ void gemm_core(
    const u16* __restrict__ Ab, int lda,
    const u16* __restrict__ Bp, int ldb,
    int m0, int n0, int K,
    u16* As, u16* Bs, f32x4 (&acc)[BM / 32][BN / 32])
{
    constexpr int FM = BM / 32, FN = BN / 32;
    constexpr int ACH = BM / 64;            // 16B chunks per thread for A
    constexpr int BCH = BN / 64;            // 16B chunks per thread for B
    const int t = threadIdx.x, lane = t & 63, w = t >> 6;
    const int wr = w >> 1, wc = w & 1, al = lane & 15, aq = lane >> 4;

    auto stage = [&](int buf, int k0) {
        u16* Ad = As + buf * (BM * 32);
        u16* Bd = Bs + buf * (BN * 32);
        #pragma unroll
        for (int i = 0; i < ACH; i++) {
            const int c = i * 256 + w * 64 + lane;           // chunk id
            gload16(Ab + (size_t)(m0 + (c >> 2)) * lda + k0 + (c & 3) * 8,
                    Ad + (size_t)(i * 256 + w * 64) * 8);
        }
        #pragma unroll
        for (int i = 0; i < BCH; i++) {
            const int c = i * 256 + w * 64 + lane;
            gload16(Bp + (size_t)(n0 + (c >> 2)) * ldb + k0 + (c & 3) * 8,
                    Bd + (size_t)(i * 256 + w * 64) * 8);
        }
    };
    auto compute = [&](int buf) {
        const u16* Ar = As + buf * (BM * 32);
        const u16* Br = Bs + buf * (BN * 32);
        s16x8 af[FM], bf[FN];
        #pragma unroll
        for (int i = 0; i < FM; i++)
            af[i] = *(const s16x8*)(Ar + ((wr * FM + i) * 16 + al) * 32 + aq * 8);
        #pragma unroll
        for (int j = 0; j < FN; j++)
            bf[j] = *(const s16x8*)(Br + ((wc * FN + j) * 16 + al) * 32 + aq * 8);
        #pragma unroll
        for (int i = 0; i < FM; i++)
            #pragma unroll
            for (int j = 0; j < FN; j++)
                acc[i][j] = __builtin_amdgcn_mfma_f32_16x16x32_bf16(af[i], bf[j], acc[i][j], 0, 0, 0);
    };

    int cur = 0;
    stage(0, 0);
    for (int k0 = 32; k0 < K; k0 += 32) {
        asm volatile("s_waitcnt vmcnt(0)" ::: "memory");
        __syncthreads();
        stage(cur ^ 1, k0);      // async: flies under compute(cur)
        compute(cur);
        cur ^= 1;
    }
    asm volatile("s_waitcnt vmcnt(0)" ::: "memory");
    __syncthreads();
    compute(cur);
}

// ---- fused Q/K/V projections: one dispatch. ----
__global__ __launch_bounds__(256, 3)
void gemm_qkv(const u16* __restrict__ qbf, const u16* __restrict__ kbf,
              const u16* __restrict__ vbf, const u16* __restrict__ wt,
              const float* __restrict__ bq, const float* __restrict__ bk,
              const float* __restrict__ bv,
              u16* __restrict__ q_ws, u16* __restrict__ k_ws,
              u16* __restrict__ vt_ws)
{
    __shared__ __attribute__((aligned(16))) u16 As[2 * 128 * 32];
    __shared__ __attribute__((aligned(16))) u16 Bs[2 * 128 * 32];
    const int flat = blockIdx.x + (blockIdx.y << 3) + (blockIdx.z << 8);
    const int z = flat >> 8;
    const int y = flat & 31;
    const int x = (flat >> 5) & 7;
    const u16* Ab = (z == 0) ? qbf : (z == 1) ? kbf : vbf;
    const u16* Bp = wt + (size_t)z * E_ * E_;
    const float* bias = (z == 0) ? bq : (z == 1) ? bk : bv;
    u16* Cb = (z == 0) ? q_ws : (z == 1) ? k_ws : vt_ws;
    const int m0 = y * 128, n0 = x * 128;

    f32x4 acc[4][4];
    #pragma unroll
    for (int i = 0; i < 4; i++)
        #pragma unroll
        for (int j = 0; j < 4; j++)
            acc[i][j] = (f32x4){0.f, 0.f, 0.f, 0.f};

    gemm_core<128, 128>(Ab, E_, Bp, E_, m0, n0, E_, As, Bs, acc);

    const int t = threadIdx.x, lane = t & 63, w = t >> 6;
    const int wr = w >> 1, wc = w & 1, al = lane & 15, aq = lane >> 4;
    #pragma unroll
    for (int i = 0; i < 4; i++) {
        #pragma unroll
        for (int j = 0; j < 4; j++) {
            const int col = n0 + (wc * 4 + j) * 16 + al;
            const float bvv = bias[col];
            #pragma unroll
            for (int r = 0; r < 4; r++) {
                const int row = m0 + (wr * 4 + i) * 16 + aq * 4 + r;
                const float vv = acc[i][j][r] + bvv;
                const int b = row >> 10, s = row & 1023, h = col >> 6, d = col & 63;
                if (z < 2)
                    Cb[((size_t)((b * H_ + h) * S_ + s)) * D_ + d] = f2bf(vv);
                else
                    Cb[((size_t)((b * H_ + h) * D_ + d)) * S_ + s] = f2bf(vv);
            }
        }
    }
}

// ---- output projection: C = ctx(bf16) @ Wo^T + bo -> f32 (nt store) ----
__global__ __launch_bounds__(256, 3)
void gemm_o(const u16* __restrict__ ctx, const u16* __restrict__ wt3,
            const float* __restrict__ bo, float* __restrict__ out)
{
    __shared__ __attribute__((aligned(16))) u16 As[2 * 128 * 32];
    __shared__ __attribute__((aligned(16))) u16 Bs[2 * 64 * 32];
    const int flat = blockIdx.x + (blockIdx.y << 4);
    const int y = flat & 31;
    const int x = flat >> 5;           // 0..15
    const int m0 = y * 128, n0 = x * 64;

    f32x4 acc[4][2];
    #pragma unroll
    for (int i = 0; i < 4; i++)
        #pragma unroll
        for (int j = 0; j < 2; j++)
            acc[i][j] = (f32x4){0.f, 0.f, 0.f, 0.f};

    gemm_core<128, 64>(ctx, E_, wt3, E_, m0, n0, E_, As, Bs, acc);

    const int t = threadIdx.x, lane = t & 63, w = t >> 6;
    const int wr = w >> 1, wc = w & 1, al = lane & 15, aq = lane >> 4;
    #pragma unroll
    for (int i = 0; i < 4; i++) {
        #pragma unroll
        for (int j = 0; j < 2; j++) {
            const int col = n0 + (wc * 2 + j) * 16 + al;
            const float bvv = bo[col];
            #pragma unroll
            for (int r = 0; r < 4; r++) {
                const int row = m0 + (wr * 4 + i) * 16 + aq * 4 + r;
                __builtin_nontemporal_store(acc[i][j][r] + bvv,
                                            &out[(size_t)row * E_ + col]);
            }
        }
    }
}

// =====================================================================
// Fused prelude: one dispatch, blocks partitioned by range.
// =====================================================================
__global__ __launch_bounds__(256)
void prelude_k(const float* __restrict__ query, const float* __restrict__ key_,
               const float* __restrict__ value,
               const float* __restrict__ Wq, const float* __restrict__ Wk,
               const float* __restrict__ Wv, const float* __restrict__ Wo,
               const float* __restrict__ Wc, const float* __restrict__ bc,
               const float* __restrict__ cl,
               u16* __restrict__ qbf, u16* __restrict__ kbf,
               u16* __restrict__ vbf, u16* __restrict__ wt,
               float* __restrict__ mws)
{
    __shared__ float tile[64][65];
    const int bid = blockIdx.x, t = threadIdx.x;

    if (bid < 512) {
        const int tid = bid * 256 + t;
        #pragma unroll
        for (int j = 0; j < 4; j++) {
            const int i = tid + j * 131072;
            {
                f32x4 a = *(const f32x4*)(query + (size_t)i * 8);
                f32x4 b = *(const f32x4*)(query + (size_t)i * 8 + 4);
                u16x8 o;
                o[0] = f2bf(a[0]); o[1] = f2bf(a[1]); o[2] = f2bf(a[2]); o[3] = f2bf(a[3]);
                o[4] = f2bf(b[0]); o[5] = f2bf(b[1]); o[6] = f2bf(b[2]); o[7] = f2bf(b[3]);
                *(u16x8*)(qbf + (size_t)i * 8) = o;
            }
            {
                f32x4 a = *(const f32x4*)(key_ + (size_t)i * 8);
                f32x4 b = *(const f32x4*)(key_ + (size_t)i * 8 + 4);
                u16x8 o;
                o[0] = f2bf(a[0]); o[1] = f2bf(a[1]); o[2] = f2bf(a[2]); o[3] = f2bf(a[3]);
                o[4] = f2bf(b[0]); o[5] = f2bf(b[1]); o[6] = f2bf(b[2]); o[7] = f2bf(b[3]);
                *(u16x8*)(kbf + (size_t)i * 8) = o;
            }
            {
                f32x4 a = *(const f32x4*)(value + (size_t)i * 8);
                f32x4 b = *(const f32x4*)(value + (size_t)i * 8 + 4);
                u16x8 o;
                o[0] = f2bf(a[0]); o[1] = f2bf(a[1]); o[2] = f2bf(a[2]); o[3] = f2bf(a[3]);
                o[4] = f2bf(b[0]); o[5] = f2bf(b[1]); o[6] = f2bf(b[2]); o[7] = f2bf(b[3]);
                *(u16x8*)(vbf + (size_t)i * 8) = o;
            }
        }
    } else if (bid < 1536) {
        const int tb = bid - 512;
        const int zz = tb >> 8, rem = tb & 255;
        const int by = (rem >> 4) * 64, bx = (rem & 15) * 64;
        const float* in = (zz == 0) ? Wq : (zz == 1) ? Wk : (zz == 2) ? Wv : Wo;
        u16* o = wt + (size_t)zz * E_ * E_;
        const int tx = t & 63, ty = t >> 6;       // 64 cols x 4 rows
        #pragma unroll
        for (int i = 0; i < 16; i++) {
            const int r = ty + i * 4;
            tile[r][tx] = in[(size_t)(by + r) * E_ + bx + tx];
        }
        __syncthreads();
        #pragma unroll
        for (int i = 0; i < 16; i++) {
            const int r = ty + i * 4;
            o[(size_t)(bx + r) * E_ + by + tx] = f2bf(tile[tx][r]);
        }
    } else {
        const int lane = t & 63, wave = t >> 6;
        const int r = (bid - 1536) * 4 + wave;    // row in [0, B*S)
        const float* qrow = query + (size_t)r * E_;
        float acc[H_];
        #pragma unroll
        for (int c = 0; c < H_; c++) acc[c] = 0.f;
        for (int e = lane; e < E_; e += 64) {
            float qv = qrow[e];
            const float* wp = Wc + e * H_;
            f32x4 w0 = *(const f32x4*)(wp);
            f32x4 w1 = *(const f32x4*)(wp + 4);
            f32x4 w2 = *(const f32x4*)(wp + 8);
            f32x4 w3 = *(const f32x4*)(wp + 12);
            #pragma unroll
            for (int c = 0; c < 4; c++) {
                acc[c]      += qv * w0[c];
                acc[4 + c]  += qv * w1[c];
                acc[8 + c]  += qv * w2[c];
                acc[12 + c] += qv * w3[c];
            }
        }
        #pragma unroll
        for (int c = 0; c < H_; c++) acc[c] = wave_sum(acc[c]);
        float mx = -3e38f;
        #pragma unroll
        for (int c = 0; c < H_; c++) { acc[c] += bc[c]; mx = fmaxf(mx, acc[c]); }
        float se = 0.f;
        #pragma unroll
        for (int c = 0; c < H_; c++) { acc[c] = __expf(acc[c] - mx); se += acc[c]; }
        if (lane < H_) {
            float mycw = 0.f;
            #pragma unroll
            for (int c = 0; c < H_; c++) if (lane == c) mycw = acc[c];
            mycw /= se;
            int b = r >> 10, s = r & 1023;
            float clv = cl[r];
            mws[((size_t)(b * H_ + lane)) * S_ + s] = 1.f + clv * mycw;
        }
    }
}

// ---- Vsum[bh][d] = sum_k V^T[bh][d][k] (bias-inclusive) ----
__global__ __launch_bounds__(256)
void vsum_k(const u16* __restrict__ vt_ws, float* __restrict__ vsum)
{
    const int bh = blockIdx.x;
    const int t = threadIdx.x, lane = t & 63, ww = t >> 6;
    #pragma unroll
    for (int dd = 0; dd < 16; dd++) {
        const int d = ww * 16 + dd;
        const u16* row = vt_ws + ((size_t)bh * D_ + d) * S_;
        float s = 0.f;
        #pragma unroll
        for (int c = 0; c < 2; c++) {
            u16x8 v = *(const u16x8*)(row + (size_t)(c * 64 + lane) * 8);
            #pragma unroll
            for (int j = 0; j < 8; j++) s += bf2f(v[j]);
        }
        s = wave_sum(s);
        if (lane == 0) vsum[bh * D_ + d] = s;
    }
}

// =====================================================================
// Fused attention with causal work-skipping. 512 threads (8 waves),
// one (b,h) x 16-row Q tile. Swapped-operand MFMA (D: col=q, row=k).
//   - fully-masked (wave,k-tile) pairs skip QK^T MFMA + K loads + exp
//     (both passes): ~49% of phase-1 work eliminated on average.
//   - P' = e2 - 1 staged to LDS (0 on masked region) -> PV skips
//     fully-masked k-slabs (~49% of PV MFMA + V reads); exact
//     correction O = (sum P'V + Vsum) * invZ, Z = sum P' + S.
//   - attn written as (P'+1)*invZ (bitwise identical to e2*invZ).
// =====================================================================
#define LDS_ 1028   // f32 row stride
__global__ __launch_bounds__(512, 4)
void attn_fused(const u16* __restrict__ q_ws, const u16* __restrict__ k_ws,
                const u16* __restrict__ vt_ws, const float* __restrict__ mws,
                const float* __restrict__ vsum,
                float* __restrict__ attn_out, u16* __restrict__ ctx_ws,
                float alpha)
{
    __shared__ __attribute__((aligned(16))) float Sf[16 * LDS_]; // 65792B
    float* dmp = Sf;                    // [8][64][20] f32 (reduction, after barrier)
    __shared__ float red[8 * 16];
    __shared__ float sclA[16], invzA[16];

    const int t = threadIdx.x, lane = t & 63, w = t >> 6;
    const int al = lane & 15, aq = lane >> 4;
    const int bh = blockIdx.x;          // bh%8 = XCD -> K/V L2-resident
    const int q0 = blockIdx.y << 4;

    const u16* Qp = q_ws + ((size_t)bh * S_ + q0) * D_;
    const u16* Kp = k_ws + ((size_t)bh * S_ + w * 128) * D_;
    const u16* Vp = vt_ws + (size_t)bh * D_ * S_;

    // causal work bounds for this wave (k-range [w*128, w*128+128))
    const int lim = q0 + 15 - w * 128;                 // highest needed k-offset
    const int nmf = (lim < 0) ? 0 : ((lim >> 4) + 1 > 8 ? 8 : (lim >> 4) + 1);
    const int nks = (lim < 0) ? 0 : ((lim >> 5) + 1 > 4 ? 4 : (lim >> 5) + 1);

    // ---------- phase 1: scores + exp (active tiles only) ----------
    s16x8 qb0 = *(const s16x8*)(Qp + (size_t)al * D_ + aq * 8);
    s16x8 qb1 = *(const s16x8*)(Qp + (size_t)al * D_ + 32 + aq * 8);
    const int qg = q0 + al;             // this thread's q (column)
    f32x4 ee[8];
    float s1 = 0.f;
    #pragma unroll
    for (int mf = 0; mf < 8; mf++) {
        if (mf < nmf) {
            const u16* kr = Kp + (size_t)(mf * 16 + al) * D_ + aq * 8;
            s16x8 ka0 = *(const s16x8*)(kr);
            s16x8 ka1 = *(const s16x8*)(kr + 32);
            f32x4 a0 = (f32x4){0.f, 0.f, 0.f, 0.f};
            a0 = __builtin_amdgcn_mfma_f32_16x16x32_bf16(ka0, qb0, a0, 0, 0, 0);
            a0 = __builtin_amdgcn_mfma_f32_16x16x32_bf16(ka1, qb1, a0, 0, 0, 0);
            const int k0i = w * 128 + mf * 16 + aq * 4;
            #pragma unroll
            for (int r = 0; r < 4; r++) {
                float e = (k0i + r <= qg) ? __expf(a0[r] * alpha) : 0.f;
                ee[mf][r] = e;
                s1 += e;
            }
        }
    }
    s1 += __shfl_xor(s1, 16);
    s1 += __shfl_xor(s1, 32);
    if (lane < 16) red[w * 16 + al] = s1;
    __syncthreads();
    if (t < 16) {
        float s = 0.f;
        #pragma unroll
        for (int c = 0; c < 8; c++) s += red[c * 16 + t];
        sclA[t] = mws[(size_t)bh * S_ + q0 + t] / s;   // m / sum1
    }
    __syncthreads();

    // ---------- pass 3: P' = e2-1 (0 on masked), stage to LDS ----------
    const float sl = sclA[al];
    float s2 = 0.f;
    #pragma unroll
    for (int mf = 0; mf < 8; mf++) {
        const int k0i = w * 128 + mf * 16 + aq * 4;
        f32x4 o4;
        if (mf < nmf) {
            #pragma unroll
            for (int r = 0; r < 4; r++) {
                float e = (k0i + r <= qg) ? (__expf(ee[mf][r] * sl) - 1.f) : 0.f;
                o4[r] = e;
                s2 += e;
            }
        } else {
            o4 = (f32x4){0.f, 0.f, 0.f, 0.f};
        }
        *(f32x4*)(Sf + (size_t)al * LDS_ + k0i) = o4;
    }
    s2 += __shfl_xor(s2, 16);
    s2 += __shfl_xor(s2, 32);
    if (lane < 16) red[w * 16 + al] = s2;
    __syncthreads();
    if (t < 16) {
        float s = 0.f;
        #pragma unroll
        for (int c = 0; c < 8; c++) s += red[c * 16 + t];
        invzA[t] = 1.f / (s + (float)S_);              // Z = sum P' + S
    }
    __syncthreads();

    // ---------- attn write: (P'+1)*invZ, coalesced nt f32x4 ----------
    float* ao = attn_out + (size_t)bh * S_ * S_ + (size_t)q0 * S_;
    #pragma unroll
    for (int rr = 0; rr < 2; rr++) {
        const int r2 = w * 2 + rr;
        const float iz = invzA[r2];
        #pragma unroll
        for (int k2 = 0; k2 < 4; k2++) {
            f32x4 v = *(const f32x4*)(Sf + (size_t)r2 * LDS_ + k2 * 256 + lane * 4);
            f32x4 o;
            #pragma unroll
            for (int j = 0; j < 4; j++) o[j] = (v[j] + 1.f) * iz;
            __builtin_nontemporal_store(o, (f32x4*)(ao + (size_t)r2 * S_ + k2 * 256 + lane * 4));
        }
    }

    // ---------- PV partials over active k-slabs only ----------
    f32x4 pa[4];
    #pragma unroll
    for (int nf = 0; nf < 4; nf++) pa[nf] = (f32x4){0.f, 0.f, 0.f, 0.f};
    #pragma unroll
    for (int ks = 0; ks < 4; ks++) {
        if (ks < nks) {
            const int kb = w * 128 + ks * 32;
            const float* ap = Sf + (size_t)al * LDS_ + kb + aq * 8;
            f32x4 x0 = *(const f32x4*)(ap);
            f32x4 x1 = *(const f32x4*)(ap + 4);
            s16x8 af;
            af[0] = (short)f2bf(x0[0]); af[1] = (short)f2bf(x0[1]);
            af[2] = (short)f2bf(x0[2]); af[3] = (short)f2bf(x0[3]);
            af[4] = (short)f2bf(x1[0]); af[5] = (short)f2bf(x1[1]);
            af[6] = (short)f2bf(x1[2]); af[7] = (short)f2bf(x1[3]);
            #pragma unroll
            for (int nf = 0; nf < 4; nf++) {
                s16x8 bv = *(const s16x8*)(Vp + (size_t)(nf * 16 + al) * S_ + kb + aq * 8);
                pa[nf] = __builtin_amdgcn_mfma_f32_16x16x32_bf16(af, bv, pa[nf], 0, 0, 0);
            }
        }
    }
    __syncthreads();   // all Sf reads done -> reuse LDS as reduction scratch

    // ---------- cross-wave ctx reduction + Vsum correction ----------
    {
        float* dp = dmp + w * (64 * 20);
        #pragma unroll
        for (int nf = 0; nf < 4; nf++)
            *(f32x4*)(dp + (size_t)(nf * 16 + al) * 20 + aq * 4) = pa[nf];
    }
    __syncthreads();
    {
        const int r5 = t >> 5, d0 = (t & 31) * 2;
        const float iz = invzA[r5];
        float o0 = 0.f, o1 = 0.f;
        #pragma unroll
        for (int ww = 0; ww < 8; ww++) {
            const float* rp5 = dmp + ww * (64 * 20) + r5;
            o0 += rp5[(size_t)d0 * 20];
            o1 += rp5[(size_t)(d0 + 1) * 20];
        }
        o0 += vsum[bh * D_ + d0];
        o1 += vsum[bh * D_ + d0 + 1];
        const int b = bh >> 4, h = bh & 15;
        u16* cp = ctx_ws + ((size_t)(b * S_ + q0 + r5)) * E_ + h * 64 + d0;
        u16x2 ob;
        ob[0] = f2bf(o0 * iz);
        ob[1] = f2bf(o1 * iz);
        *(u16x2*)cp = ob;
    }
}

extern "C" void kernel_launch(void* const* d_in, const int* in_sizes, int n_in,
                              void* d_out, int out_size, void* d_ws, size_t ws_size,
                              hipStream_t stream)
{
    const float* query = (const float*)d_in[0];
    const float* key_  = (const float*)d_in[1];
    const float* value = (const float*)d_in[2];
    const float* cl    = (const float*)d_in[3];
    // d_in[4] = attn_mask (tril, constant) -- causality handled analytically
    const float* Wq = (const float*)d_in[5];
    const float* bq = (const float*)d_in[6];
    const float* Wk = (const float*)d_in[7];
    const float* bk = (const float*)d_in[8];
    const float* Wv = (const float*)d_in[9];
    const float* bv = (const float*)d_in[10];
    const float* Wo = (const float*)d_in[11];
    const float* bo = (const float*)d_in[12];
    const float* Wc = (const float*)d_in[13];
    const float* bc = (const float*)d_in[14];
    // d_in[15] = phi_bias: per-row constant inside softmax1 -> cancels

    float* out  = (float*)d_out;
    float* attn = out + (size_t)B_ * S_ * E_;        // [B][H][S][S] f32

    u16* q_ws   = (u16*)d_ws;                        // [B][H][S][D] bf16
    u16* k_ws   = q_ws  + (size_t)B_ * S_ * E_;      // [B][H][S][D]
    u16* vt_ws  = k_ws  + (size_t)B_ * S_ * E_;      // [B][H][D][S]
    u16* ctx_ws = vt_ws + (size_t)B_ * S_ * E_;      // [B][S][E]
    u16* wt     = ctx_ws + (size_t)B_ * S_ * E_;     // 4 x [E][E] bf16 W^T
    float* mws  = (float*)(wt + (size_t)4 * E_ * E_); // [B][H][S] f32
    float* vsum = mws + (size_t)B_ * H_ * S_;        // [B*H][D] f32

    // bf16 copies of query/key/value live in the (later fully overwritten)
    // attn output region: 24 MB scratch inside the 268 MB attn buffer.
    u16* qbf = (u16*)attn;
    u16* kbf = qbf + (size_t)B_ * S_ * E_;
    u16* vbf = kbf + (size_t)B_ * S_ * E_;

    const float inv_scale = 0.09826892502579689f;    // 1/(8*sqrt(PHI))
    dim3 blk(256);

    // fused prelude: cvt3 (512 blocks) + W transposes (1024) + cons (1024)
    prelude_k<<<2560, blk, 0, stream>>>(query, key_, value, Wq, Wk, Wv, Wo,
                                        Wc, bc, cl, qbf, kbf, vbf, wt, mws);

    // fused Q/K/V projections: M=4096, N=1024, K=1024, 768 blocks (3/CU)
    gemm_qkv<<<dim3(8, 32, 3), blk, 0, stream>>>(
        qbf, kbf, vbf, wt, bq, bk, bv, q_ws, k_ws, vt_ws);

    // per-(b,h) column sums of V (for the causal-skip PV correction)
    vsum_k<<<B_ * H_, blk, 0, stream>>>(vt_ws, vsum);

    // fused scores + double-softmax + attn write + PV (16-row Q tiles)
    attn_fused<<<dim3(B_ * H_, S_ / 16), dim3(512), 0, stream>>>(
        q_ws, k_ws, vt_ws, mws, vsum, attn, ctx_ws, inv_scale);

    // output projection: M=4096, N=1024, K=1024 (A bf16); 512 blocks
    gemm_o<<<dim3(16, 32, 1), blk, 0, stream>>>(
        ctx_ws, wt + (size_t)3 * E_ * E_, bo, out);
}